// Round 15
// baseline (1038.305 us; speedup 1.0000x reference)
//
#include <hip/hip_runtime.h>
#include <hip/hip_bf16.h>

// LSTM2: B=1024, T=1024, H=64. R31: R30 (merged single-group redesign)
// with the epilogue STALE-pa BUG fixed. R30 failed absmax 3.59e-2:
// in-loop, iter t loads pa=h1(t-1); after loop exit pa holds h1(Tt-2)
// (loaded at iter Tt-1), but the epilogue's L2(Tt-1) needs h1(Tt-1).
// R30 used the stale regs -> out(:,Tt-1) computed from wrong h1 ->
// bounded few-e-2 error in one column. Fix: epilogue RELOADS pa from
// h1ring[(Tt-1)&3] (visible under the existing poll qf>=Tt: h1(Tt-1)
// written at iter Tt-1 before qf=Tt publish). No other changes.
// Design (R30): 4 waves/block (1/SIMD). Wave gw owns unit group
// 16gw..16gw+15 for BOTH layers, holds W1,W2,W3 (~200 VGPR,
// launch_bounds(256,1)). Iteration t: ai-init -> poll qf>=t -> L1(t)
// {pa=h1(t-1), 8 MFMA, mux, cell1, write h1(t)} -> L2(t-1) {pb=h2(t-2),
// 16 MFMA reusing pa, mux, cell2, write h2(t-1), headp(t-1)} ->
// round-robin out(t-2) finalize -> lane0 publish qf=t+1. ONE publish,
// ONE poll per step; same-wave DS in-order makes qf=t cover h1(t-1),
// h2(t-2), headp(t-2) at once. Tail race fixed by construction.
// Slot audit (qf>=t => all waves fully completed iter t-1):
//   h1ring depth4: write t&3 kills h1(t-4), last read iter t-3 ✓.
//   h2 parity2: write (t-1)&1 kills h2(t-3), last read iter t-1 ✓.
//   headp depth4: write (t-1)&3 kills headp(t-5), last read iter t-3 ✓.
//   t=1: L2(0) reads h2(-1)=0 from zero-init slot 1, writes slot 0 ✓.
// Epilogue: poll qf>=Tt -> reload pa=h1(Tt-1) -> L2(Tt-1) -> headp(Tt-1)
// -> publish qf=Tt+1; wave0 polls qf>=Tt+1 -> finalize out(Tt-2/Tt-1).
// Retained: batch-replicated MFMA cols + 12-cndmask register mux (lane
// (quad,m) owns (batch m&3, unit 16gw+4*(m>>2)+quad) in acc[m>>2]),
// pre-scaled activations, setprio, ai hoisted above poll, HSTR=80,
// LDS outbuf + coalesced flush, dtype sniff.
// Layouts (m89/m91/m120): A[m=lane&15][k=(lane>>4)*8+j],
// B[k=(lane>>4)*8+j][n=lane&15], C/D: row=(lane>>4)*4+reg, col=lane&15.

typedef _Float16 f16x8 __attribute__((ext_vector_type(8)));
typedef float    f32x4 __attribute__((ext_vector_type(4)));

namespace {
constexpr int Bb = 1024;
constexpr int Tt = 1024;
constexpr int NBat = 4;    // batches per block
constexpr int HSTR = 80;   // f16 stride per batch row of h (bank-tuned)
constexpr int XSTR = 1025; // f32 stride per batch row of x

// Pre-scaled activations: gate rows of W/b folded with -log2e (i,f,o) and
// -2log2e (g) at load, so no input multiply here.
__device__ __forceinline__ float sigm_pre(float a) {   // a = -1.4427*x
    return __builtin_amdgcn_rcpf(1.0f + __builtin_amdgcn_exp2f(a));
}
__device__ __forceinline__ float tanh_pre(float a) {   // a = -2.8854*x
    return fmaf(2.0f, __builtin_amdgcn_rcpf(1.0f + __builtin_amdgcn_exp2f(a)), -1.0f);
}
__device__ __forceinline__ float tanh_f(float x) {     // unscaled input (c-path)
    float e = __builtin_amdgcn_exp2f(-2.8853900817779268f * x);
    return fmaf(2.0f, __builtin_amdgcn_rcpf(1.0f + e), -1.0f);
}
// Dtype sniff (proven R2-R29).
__device__ __forceinline__ bool detect_f32(const void* w) {
    const unsigned short* p = (const unsigned short*)w;
    int sane = 0;
    for (int i = 0; i < 64; ++i) {
        int e = (p[2 * i] >> 7) & 0xFF;
        if (e >= 107 && e <= 129) ++sane;
    }
    return sane < 32;
}
__device__ __forceinline__ float ld(const void* p, int i, bool f32) {
    return f32 ? ((const float*)p)[i]
               : __bfloat162float(((const __hip_bfloat16*)p)[i]);
}
__device__ __forceinline__ void st(void* p, int i, float v, bool f32) {
    if (f32) ((float*)p)[i] = v;
    else     ((__hip_bfloat16*)p)[i] = __float2bfloat16(v);
}
// Single-group lane-parallel spin: lane i watches flg[i&3] vs thr.
// One broadcast ds_read_b32 per spin, __all ballot.
__device__ __forceinline__ void poll_flags(const int* f, int thr, int lane) {
    const int idx = lane & 3;
    for (;;) {
        int v = ((const volatile int*)f)[idx];
        if (__all(v >= thr)) break;
    }
    __builtin_amdgcn_sched_barrier(0);
    asm volatile("" ::: "memory");
}
} // namespace

__global__ __launch_bounds__(256, 1) void lstm2_kernel(
    const void* __restrict__ x,      // [B, T]
    const void* __restrict__ w_ih1,  // [256, 1]
    const void* __restrict__ w_hh1,  // [256, 64]
    const void* __restrict__ b_ih1,  // [256]
    const void* __restrict__ b_hh1,  // [256]
    const void* __restrict__ w_ih2,  // [256, 64]
    const void* __restrict__ w_hh2,  // [256, 64]
    const void* __restrict__ b_ih2,  // [256]
    const void* __restrict__ b_hh2,  // [256]
    const void* __restrict__ w_lin,  // [1, 64]
    const void* __restrict__ b_lin,  // [1]
    void* __restrict__ out)          // [B, T]
{
    const int tid  = threadIdx.x;
    const int lane = tid & 63;
    const int gw   = tid >> 6;       // wave 0..3, owns units 16gw..16gw+15
    const int m    = lane & 15;      // MFMA col
    const int quad = lane >> 4;
    const int bb   = blockIdx.x * NBat;

    const bool f32 = detect_f32(w_hh1);

    __shared__ float                  xs[NBat * XSTR];
    __shared__ __align__(16) _Float16 h1ring[4][NBat * HSTR]; // 4-deep ring
    __shared__ __align__(16) _Float16 h2buf[2][NBat * HSTR];  // parity
    __shared__ __align__(16) float    headp[4][NBat][4];      // [slot][b][gw]
    __shared__ float                  outbuf[NBat * Tt];      // staged outputs
    __shared__ int                    flg[4];                 // qf per wave

    // ---- stage x + zero h buffers (256 threads) ----
    for (int i = tid; i < NBat * 1024; i += 256)
        xs[(i >> 10) * XSTR + (i & 1023)] = ld(x, (bb + (i >> 10)) * Tt + (i & 1023), f32);
    for (int i = tid; i < NBat * HSTR; i += 256) {
        h1ring[0][i] = (_Float16)0; h1ring[1][i] = (_Float16)0;
        h1ring[2][i] = (_Float16)0; h1ring[3][i] = (_Float16)0;
        h2buf[0][i] = (_Float16)0;  h2buf[1][i] = (_Float16)0;
    }
    if (tid < 4) flg[tid] = 0;

    // ---- A-fragments, gate-interleaved rows (R13), activation-scale folded.
    // Every wave loads W1 (wf1), W2 (wf2), W3 (wf3) rows for its unit group.
    // tile row (lane&15) = 4*u_loc + g -> mem row 64*g + 16*gw + 4q + u_loc
    const int arow = lane & 15;
    const int g_ld = arow & 3;
    const int u_ld = arow >> 2;
    const float scA = (g_ld == 2) ? -2.8853900817779268f : -1.4426950408889634f;
    f16x8 wf1[4][2], wf2[4][2], wf3[4][2];
#pragma unroll
    for (int q = 0; q < 4; ++q) {
        const int row = 64 * g_ld + 16 * gw + 4 * q + u_ld;
#pragma unroll
        for (int s = 0; s < 2; ++s) {
            const int base = row * 64 + 32 * s + quad * 8;
            if (f32) {
                const float* A1 = (const float*)w_hh1;
                const float* A2 = (const float*)w_ih2;
                const float* A3 = (const float*)w_hh2;
#pragma unroll
                for (int j = 0; j < 8; ++j) {
                    wf1[q][s][j] = (_Float16)(scA * A1[base + j]);
                    wf2[q][s][j] = (_Float16)(scA * A2[base + j]);
                    wf3[q][s][j] = (_Float16)(scA * A3[base + j]);
                }
            } else {
                const __hip_bfloat16* A1 = (const __hip_bfloat16*)w_hh1;
                const __hip_bfloat16* A2 = (const __hip_bfloat16*)w_ih2;
                const __hip_bfloat16* A3 = (const __hip_bfloat16*)w_hh2;
#pragma unroll
                for (int j = 0; j < 8; ++j) {
                    wf1[q][s][j] = (_Float16)(scA * __bfloat162float(A1[base + j]));
                    wf2[q][s][j] = (_Float16)(scA * __bfloat162float(A2[base + j]));
                    wf3[q][s][j] = (_Float16)(scA * __bfloat162float(A3[base + j]));
                }
            }
        }
    }
    // biases / wx per (tile q, gate r): D row r = gate r, unit 16gw+4q+quad
    f32x4 bv1[4], bv2[4], wxv[4];
#pragma unroll
    for (int q = 0; q < 4; ++q)
#pragma unroll
        for (int r = 0; r < 4; ++r) {
            const int row = 64 * r + 16 * gw + 4 * q + quad;
            const float sg = (r == 2) ? -2.8853900817779268f : -1.4426950408889634f;
            bv1[q][r] = sg * (ld(b_ih1, row, f32) + ld(b_hh1, row, f32));
            bv2[q][r] = sg * (ld(b_ih2, row, f32) + ld(b_hh2, row, f32));
            wxv[q][r] = sg * ld(w_ih1, row, f32);
        }
    // cell ownership (batch-replicated cols): lane (quad,m) owns
    // (batch m&3, unit 16gw + 4*(m>>2) + quad), gates in acc[m>>2].
    const int q2   = m >> 2;
    const int bsel = m & 3;
    const int hidx = bsel * HSTR + 16 * gw + 4 * q2 + quad;  // own h slot
    const bool s1 = (q2 & 1) != 0, s2 = (q2 & 2) != 0;
    const float wl_u = ld(w_lin, 16 * gw + 4 * q2 + quad, f32);
    const float blin = ld(b_lin, 0, f32);
    float c1 = 0.0f, c2 = 0.0f;       // both cell states live in this wave
    f16x8 pa0{}, pa1{};               // h1(t-1) frags, reused by L2
    __syncthreads();   // xs + zeroed bufs + flags visible

#pragma unroll 4
    for (int t = 0; t < Tt; ++t) {
        // acc-init before poll: reads only static xs/regs
        const float xt = xs[bsel * XSTR + t];
        f32x4 ai[4];
#pragma unroll
        for (int q = 0; q < 4; ++q)
#pragma unroll
            for (int r = 0; r < 4; ++r)
                ai[q][r] = fmaf(xt, wxv[q][r], bv1[q][r]);
        poll_flags(flg, t, lane);     // all waves completed iter t-1 fully
        // ================= L1(t) =================
        f32x4 g1;
        if (t > 0) {
            const _Float16* hp = h1ring[(t - 1) & 3] + bsel * HSTR;
            pa0 = *(const f16x8*)(hp + quad * 8);
            pa1 = *(const f16x8*)(hp + 32 + quad * 8);
            f32x4 acc[4];
            __builtin_amdgcn_s_setprio(1);
#pragma unroll
            for (int q = 0; q < 4; ++q) {   // depth-1: independent k-halves
                f32x4 p0 = __builtin_amdgcn_mfma_f32_16x16x32_f16(wf1[q][0], pa0, ai[q], 0, 0, 0);
                f32x4 p1 = __builtin_amdgcn_mfma_f32_16x16x32_f16(wf1[q][1], pa1, f32x4{0,0,0,0}, 0, 0, 0);
                acc[q] = p0 + p1;
            }
            __builtin_amdgcn_s_setprio(0);
#pragma unroll
            for (int r = 0; r < 4; ++r) {   // register mux: g1 = acc[q2]
                float lo = s1 ? acc[1][r] : acc[0][r];
                float hi = s1 ? acc[3][r] : acc[2][r];
                g1[r] = s2 ? hi : lo;
            }
        } else {
#pragma unroll
            for (int r = 0; r < 4; ++r)
                g1[r] = s2 ? (s1 ? ai[3][r] : ai[2][r])
                           : (s1 ? ai[1][r] : ai[0][r]);
        }
        {   // cell1 (1 per lane)
            float ig = sigm_pre(g1[0]), fg = sigm_pre(g1[1]);
            float gg = tanh_pre(g1[2]), og = sigm_pre(g1[3]);
            c1 = fmaf(fg, c1, ig * gg);
            h1ring[t & 3][hidx] = (_Float16)(og * tanh_f(c1));
        }
        // ================= L2(t-1): reuses pa (h1(t-1)) =================
        if (t > 0) {
            const _Float16* h2p = h2buf[t & 1] + bsel * HSTR;   // h2(t-2)
            const f16x8 pb0 = *(const f16x8*)(h2p + quad * 8);
            const f16x8 pb1 = *(const f16x8*)(h2p + 32 + quad * 8);
            f32x4 acc[4];
            __builtin_amdgcn_s_setprio(1);
#pragma unroll
            for (int q = 0; q < 4; ++q) {   // two independent 2-deep chains
                f32x4 p2 = __builtin_amdgcn_mfma_f32_16x16x32_f16(wf2[q][0], pa0, bv2[q], 0, 0, 0);
                p2 = __builtin_amdgcn_mfma_f32_16x16x32_f16(wf2[q][1], pa1, p2, 0, 0, 0);
                f32x4 p3 = __builtin_amdgcn_mfma_f32_16x16x32_f16(wf3[q][0], pb0, f32x4{0,0,0,0}, 0, 0, 0);
                p3 = __builtin_amdgcn_mfma_f32_16x16x32_f16(wf3[q][1], pb1, p3, 0, 0, 0);
                acc[q] = p2 + p3;
            }
            __builtin_amdgcn_s_setprio(0);
            f32x4 g2;
#pragma unroll
            for (int r = 0; r < 4; ++r) {
                float lo = s1 ? acc[1][r] : acc[0][r];
                float hi = s1 ? acc[3][r] : acc[2][r];
                g2[r] = s2 ? hi : lo;
            }
            float ig = sigm_pre(g2[0]), fg = sigm_pre(g2[1]);
            float gg = tanh_pre(g2[2]), og = sigm_pre(g2[3]);
            c2 = fmaf(fg, c2, ig * gg);
            float h = og * tanh_f(c2);
            h2buf[(t - 1) & 1][hidx] = (_Float16)h;
            float p = h * wl_u;               // head partial over own 16 units
            p += __shfl_xor(p, 4);
            p += __shfl_xor(p, 8);
            p += __shfl_xor(p, 16);
            p += __shfl_xor(p, 32);
            if (lane < NBat)                   // lane==bsel: full slice sum
                headp[(t - 1) & 3][lane][gw] = p;
        }
        // ---- finalize out(t-2): round-robin wave (headp(t-2) visible) ----
        if (t >= 2 && gw == (t & 3) && lane < NBat) {
            f32x4 v = *(const f32x4*)&headp[(t - 2) & 3][lane][0];
            outbuf[lane * Tt + (t - 2)] = blin + (v[0] + v[1]) + (v[2] + v[3]);
        }
        // ---- single publish: everything above is ordered before it ----
        if (lane == 0) {
            asm volatile("" ::: "memory");
            *(volatile int*)&flg[gw] = t + 1;
        }
    }

    // ================= epilogue: L2(Tt-1) =================
    poll_flags(flg, Tt, lane);        // h1(Tt-1), h2(Tt-2) visible in LDS
    {
        // R31 FIX: reload pa from LDS -- loop-exit pa holds h1(Tt-2), but
        // L2(Tt-1) needs h1(Tt-1) (written at iter Tt-1, visible per poll).
        const _Float16* hp = h1ring[(Tt - 1) & 3] + bsel * HSTR;
        pa0 = *(const f16x8*)(hp + quad * 8);
        pa1 = *(const f16x8*)(hp + 32 + quad * 8);
        const _Float16* h2p = h2buf[Tt & 1] + bsel * HSTR;      // h2(Tt-2)
        const f16x8 pb0 = *(const f16x8*)(h2p + quad * 8);
        const f16x8 pb1 = *(const f16x8*)(h2p + 32 + quad * 8);
        f32x4 acc[4];
#pragma unroll
        for (int q = 0; q < 4; ++q) {
            f32x4 p2 = __builtin_amdgcn_mfma_f32_16x16x32_f16(wf2[q][0], pa0, bv2[q], 0, 0, 0);
            p2 = __builtin_amdgcn_mfma_f32_16x16x32_f16(wf2[q][1], pa1, p2, 0, 0, 0);
            f32x4 p3 = __builtin_amdgcn_mfma_f32_16x16x32_f16(wf3[q][0], pb0, f32x4{0,0,0,0}, 0, 0, 0);
            p3 = __builtin_amdgcn_mfma_f32_16x16x32_f16(wf3[q][1], pb1, p3, 0, 0, 0);
            acc[q] = p2 + p3;
        }
        f32x4 g2;
#pragma unroll
        for (int r = 0; r < 4; ++r) {
            float lo = s1 ? acc[1][r] : acc[0][r];
            float hi = s1 ? acc[3][r] : acc[2][r];
            g2[r] = s2 ? hi : lo;
        }
        float ig = sigm_pre(g2[0]), fg = sigm_pre(g2[1]);
        float gg = tanh_pre(g2[2]), og = sigm_pre(g2[3]);
        c2 = fmaf(fg, c2, ig * gg);
        float h = og * tanh_f(c2);
        float p = h * wl_u;
        p += __shfl_xor(p, 4);
        p += __shfl_xor(p, 8);
        p += __shfl_xor(p, 16);
        p += __shfl_xor(p, 32);
        if (lane < NBat) headp[(Tt - 1) & 3][lane][gw] = p;
    }
    if (lane == 0) {
        asm volatile("" ::: "memory");
        *(volatile int*)&flg[gw] = Tt + 1;
    }
    // ---- tail: out(Tt-2), out(Tt-1) after all epilogue headp visible ----
    if (gw == 0) {
        poll_flags(flg, Tt + 1, lane);
        if (lane < NBat) {
            f32x4 v2 = *(const f32x4*)&headp[(Tt - 2) & 3][lane][0];
            outbuf[lane * Tt + (Tt - 2)] = blin + (v2[0] + v2[1]) + (v2[2] + v2[3]);
            f32x4 v1 = *(const f32x4*)&headp[(Tt - 1) & 3][lane][0];
            outbuf[lane * Tt + (Tt - 1)] = blin + (v1[0] + v1[1]) + (v1[2] + v1[3]);
        }
    }
    __syncthreads();
    // ---- cooperative coalesced flush: LDS outbuf -> global out ----
    for (int i = tid; i < NBat * Tt; i += 256)
        st(out, (bb + (i >> 10)) * Tt + (i & 1023), outbuf[i], f32);
}

extern "C" void kernel_launch(void* const* d_in, const int* in_sizes, int n_in,
                              void* d_out, int out_size, void* d_ws, size_t ws_size,
                              hipStream_t stream)
{
    (void)in_sizes; (void)n_in; (void)out_size; (void)d_ws; (void)ws_size;
    lstm2_kernel<<<dim3(Bb / NBat), dim3(256), 0, stream>>>(
        d_in[0], d_in[1], d_in[2], d_in[3], d_in[4], d_in[5],
        d_in[6], d_in[7], d_in[8], d_in[9], d_in[10], d_out);
}

// Round 16
// 724.039 us; speedup vs baseline: 1.4340x; 1.4340x over previous
//
#include <hip/hip_runtime.h>
#include <hip/hip_bf16.h>

// LSTM2: B=1024, T=1024, H=64. R32: R29 (best race-free, 724us) with ONE
// variable changed: h1 ring depth 4 -> 8 (ELASTIC DECOUPLING).
// R31 post-mortem (1038us): merged single-wave design serializes L1+L2 in
// program order with no co-resident wave to fill stalls -- the P/Q split's
// cross-wave parallelism is worth more than its sync hops. R29 stands.
// R32 theory: with depth-4 ring P leads Q by <=3; the gap rides the cap,
// so Q jitter back-propagates to P via ring credit and P jitter forward-
// propagates to Q, every step (period = max chain + coupled noise).
// Depth-8 ring + credit t-7 gives elastic slack that ABSORBS jitter:
// each group paces at its own rate, noise is smoothed by the buffer.
// Audit of the one change: P writes h1ring[t&7], overwriting h1(t-8).
// Readers of h1(t-8): Q at step t-8 (guarded: credit poll qf>=t-7 <=>
// all Q completed step t-8) and P at step t-7 (own pf>=t covers). h2buf
// (parity-2) + headp (depth-4) are Q-INTERNAL (Q group spread <=1,
// unaffected by the P/Q gap). LDS +2.5KB. flg2 tail fix retained.
// R29 recap: decoupled P/Q flag pipelines; batch-replicated MFMA cols
// (B col n = batch n&3; lane (quad,m) owns cell (batch m&3, unit
// 16gw+4*(m>>2)+quad) in acc[m>>2]; 12-cndmask register mux -- no scr
// LDS roundtrip); Q publishes right after h2 write, head partial after
// publish (w4 reads headp at lag 2); pre-scaled activations; depth-1 P
// MFMAs; 2-deep Q chains; setprio; ai-init hoisted above poll; HSTR=80;
// LDS outbuf + coalesced flush; flg2 tail-done flags (R27 race fix).
// Protocol: flg[0..3]=pf, flg[4..7]=qf; lane-0 publish after guarded
// ds_write (same-wave DS in-order). P(t): min(pf)>=t && min(qf)>=t-7.
// Q(u): min(pf)>=u+1 && min(qf)>=u.
// Layouts (m89/m91/m120): A[m=lane&15][k=(lane>>4)*8+j],
// B[k=(lane>>4)*8+j][n=lane&15], C/D: row=(lane>>4)*4+reg, col=lane&15.

typedef _Float16 f16x8 __attribute__((ext_vector_type(8)));
typedef float    f32x4 __attribute__((ext_vector_type(4)));

namespace {
constexpr int Bb = 1024;
constexpr int Tt = 1024;
constexpr int NBat = 4;    // batches per block
constexpr int RING = 8;    // h1 ring depth (R32: was 4)
constexpr int HSTR = 80;   // f16 stride per batch row of h (bank-tuned)
constexpr int XSTR = 1025; // f32 stride per batch row of x

// Pre-scaled activations: gate rows of W/b folded with -log2e (i,f,o) and
// -2log2e (g) at load, so no input multiply here.
__device__ __forceinline__ float sigm_pre(float a) {   // a = -1.4427*x
    return __builtin_amdgcn_rcpf(1.0f + __builtin_amdgcn_exp2f(a));
}
__device__ __forceinline__ float tanh_pre(float a) {   // a = -2.8854*x
    return fmaf(2.0f, __builtin_amdgcn_rcpf(1.0f + __builtin_amdgcn_exp2f(a)), -1.0f);
}
__device__ __forceinline__ float tanh_f(float x) {     // unscaled input (c-path)
    float e = __builtin_amdgcn_exp2f(-2.8853900817779268f * x);
    return fmaf(2.0f, __builtin_amdgcn_rcpf(1.0f + e), -1.0f);
}
// Dtype sniff (proven R2-R31).
__device__ __forceinline__ bool detect_f32(const void* w) {
    const unsigned short* p = (const unsigned short*)w;
    int sane = 0;
    for (int i = 0; i < 64; ++i) {
        int e = (p[2 * i] >> 7) & 0xFF;
        if (e >= 107 && e <= 129) ++sane;
    }
    return sane < 32;
}
__device__ __forceinline__ float ld(const void* p, int i, bool f32) {
    return f32 ? ((const float*)p)[i]
               : __bfloat162float(((const __hip_bfloat16*)p)[i]);
}
__device__ __forceinline__ void st(void* p, int i, float v, bool f32) {
    if (f32) ((float*)p)[i] = v;
    else     ((__hip_bfloat16*)p)[i] = __float2bfloat16(v);
}
// Lane-parallel spin: lane i watches flg[i&7]; P-flags (idx<4) against tp,
// Q-flags against tq. ONE broadcast ds_read_b32 per spin, __all ballot.
__device__ __forceinline__ void poll_flags(const int* f, int tp, int tq, int lane) {
    const int idx = lane & 7;
    const int thr = (idx < 4) ? tp : tq;
    for (;;) {
        int v = ((const volatile int*)f)[idx];
        if (__all(v >= thr)) break;
    }
    __builtin_amdgcn_sched_barrier(0);
    asm volatile("" ::: "memory");
}
} // namespace

__global__ __launch_bounds__(512, 1) void lstm2_kernel(
    const void* __restrict__ x,      // [B, T]
    const void* __restrict__ w_ih1,  // [256, 1]
    const void* __restrict__ w_hh1,  // [256, 64]
    const void* __restrict__ b_ih1,  // [256]
    const void* __restrict__ b_hh1,  // [256]
    const void* __restrict__ w_ih2,  // [256, 64]
    const void* __restrict__ w_hh2,  // [256, 64]
    const void* __restrict__ b_ih2,  // [256]
    const void* __restrict__ b_hh2,  // [256]
    const void* __restrict__ w_lin,  // [1, 64]
    const void* __restrict__ b_lin,  // [1]
    void* __restrict__ out)          // [B, T]
{
    const int tid  = threadIdx.x;
    const int lane = tid & 63;
    const int w    = tid >> 6;       // wave 0..7
    const int gw   = w & 3;          // group-local wave -> unit group 16gw..
    const bool isP = w < 4;          // P: L1 recurrence; Q: L2 pipeline
    const int m    = lane & 15;      // MFMA col
    const int quad = lane >> 4;
    const int bb   = blockIdx.x * NBat;

    const bool f32 = detect_f32(w_hh1);

    __shared__ float                  xs[NBat * XSTR];
    __shared__ __align__(16) _Float16 h1ring[RING][NBat * HSTR]; // 8-deep ring
    __shared__ __align__(16) _Float16 h2buf[2][NBat * HSTR];  // parity (Q)
    __shared__ __align__(16) float    headp[4][NBat][4];      // [u&3][b][gw]
    __shared__ float                  outbuf[NBat * Tt];      // staged outputs
    __shared__ int                    flg[8];                 // 0..3 pf, 4..7 qf
    __shared__ int                    flg2[4];                // tail-done per Q wave

    // ---- stage x + zero h buffers ----
    for (int i = tid; i < NBat * 1024; i += 512)
        xs[(i >> 10) * XSTR + (i & 1023)] = ld(x, (bb + (i >> 10)) * Tt + (i & 1023), f32);
    for (int i = tid; i < NBat * HSTR; i += 512) {
#pragma unroll
        for (int rr = 0; rr < RING; ++rr) h1ring[rr][i] = (_Float16)0;
        h2buf[0][i] = (_Float16)0;  h2buf[1][i] = (_Float16)0;
    }
    if (tid < 8) flg[tid] = 0;
    if (tid < 4) flg2[tid] = 0;

    // ---- A-fragments, gate-interleaved rows (R13), activation-scale folded ----
    // tile row (lane&15) = 4*u_loc + g -> mem row 64*g + 16*gw + 4q + u_loc
    const int arow = lane & 15;
    const int g_ld = arow & 3;
    const int u_ld = arow >> 2;
    const float scA = (g_ld == 2) ? -2.8853900817779268f : -1.4426950408889634f;
    f16x8 wfA[4][2], wfB[4][2];   // P: wfA=W1 (wfB zero); Q: wfA=W2, wfB=W3
    {
        const void* MA = isP ? w_hh1 : w_ih2;
#pragma unroll
        for (int q = 0; q < 4; ++q) {
            const int row = 64 * g_ld + 16 * gw + 4 * q + u_ld;
#pragma unroll
            for (int s = 0; s < 2; ++s) {
                const int base = row * 64 + 32 * s + quad * 8;
                if (f32) {
                    const float* A = (const float*)MA;
                    const float* B = (const float*)w_hh2;
#pragma unroll
                    for (int j = 0; j < 8; ++j) {
                        wfA[q][s][j] = (_Float16)(scA * A[base + j]);
                        wfB[q][s][j] = isP ? (_Float16)0.0f
                                           : (_Float16)(scA * B[base + j]);
                    }
                } else {
                    const __hip_bfloat16* A = (const __hip_bfloat16*)MA;
                    const __hip_bfloat16* B = (const __hip_bfloat16*)w_hh2;
#pragma unroll
                    for (int j = 0; j < 8; ++j) {
                        wfA[q][s][j] = (_Float16)(scA * __bfloat162float(A[base + j]));
                        wfB[q][s][j] = isP ? (_Float16)0.0f
                                           : (_Float16)(scA * __bfloat162float(B[base + j]));
                    }
                }
            }
        }
    }
    // bias / wx per (tile q, gate r): D row r of tile q = gate r, unit 16gw+4q+quad
    f32x4 bv[4], wxv[4];
#pragma unroll
    for (int q = 0; q < 4; ++q)
#pragma unroll
        for (int r = 0; r < 4; ++r) {
            const int row = 64 * r + 16 * gw + 4 * q + quad;
            const float sg = (r == 2) ? -2.8853900817779268f : -1.4426950408889634f;
            bv[q][r] = sg * (isP ? (ld(b_ih1, row, f32) + ld(b_hh1, row, f32))
                                 : (ld(b_ih2, row, f32) + ld(b_hh2, row, f32)));
            wxv[q][r] = isP ? sg * ld(w_ih1, row, f32) : 0.0f;
        }
    // cell ownership (batch-replicated cols): lane (quad,m) owns
    // (batch m&3, unit 16gw + 4*(m>>2) + quad), gates in acc[m>>2].
    const int q2   = m >> 2;
    const int bsel = m & 3;
    const int hidx = bsel * HSTR + 16 * gw + 4 * q2 + quad;  // own h slot
    const bool s1 = (q2 & 1) != 0, s2 = (q2 & 2) != 0;
    const float wl_u = ld(w_lin, 16 * gw + 4 * q2 + quad, f32);
    const float blin = ld(b_lin, 0, f32);
    float cst = 0.0f;                 // c-state of the owned cell
    __syncthreads();   // xs + zeroed bufs + flags visible

    if (isP) {
        // ================= P: L1 recurrence, self-paced =================
#pragma unroll 4
        for (int t = 0; t < Tt; ++t) {
            // acc-init before poll: reads only static xs/regs
            const float xt = xs[bsel * XSTR + t];
            f32x4 ai[4];
#pragma unroll
            for (int q = 0; q < 4; ++q)
#pragma unroll
                for (int r = 0; r < 4; ++r)
                    ai[q][r] = fmaf(xt, wxv[q][r], bv[q][r]);
            poll_flags(flg, t, t - (RING - 1), lane); // group sync + ring credit
            f32x4 acc[4];
            if (t > 0) {
                const _Float16* hp = h1ring[(t - 1) & (RING - 1)] + bsel * HSTR;
                const f16x8 pa0 = *(const f16x8*)(hp + quad * 8);
                const f16x8 pa1 = *(const f16x8*)(hp + 32 + quad * 8);
                __builtin_amdgcn_s_setprio(1);
#pragma unroll
                for (int q = 0; q < 4; ++q) {   // depth-1: independent k-halves
                    f32x4 p0 = __builtin_amdgcn_mfma_f32_16x16x32_f16(wfA[q][0], pa0, ai[q], 0, 0, 0);
                    f32x4 p1 = __builtin_amdgcn_mfma_f32_16x16x32_f16(wfA[q][1], pa1, f32x4{0,0,0,0}, 0, 0, 0);
                    acc[q] = p0 + p1;
                }
                __builtin_amdgcn_s_setprio(0);
            } else {
#pragma unroll
                for (int q = 0; q < 4; ++q) acc[q] = ai[q];
            }
            // ---- register mux: g = acc[q2] (12 cndmasks, no LDS) ----
            f32x4 g;
#pragma unroll
            for (int r = 0; r < 4; ++r) {
                float lo = s1 ? acc[1][r] : acc[0][r];
                float hi = s1 ? acc[3][r] : acc[2][r];
                g[r] = s2 ? hi : lo;
            }
            // ---- cell (1 per lane) ----
            float ig = sigm_pre(g[0]), fg = sigm_pre(g[1]);
            float gg = tanh_pre(g[2]), og = sigm_pre(g[3]);
            cst = fmaf(fg, cst, ig * gg);
            h1ring[t & (RING - 1)][hidx] = (_Float16)(og * tanh_f(cst));
            if (lane == 0) {          // publish: DS in-order, no waitcnt
                asm volatile("" ::: "memory");
                *(volatile int*)&flg[gw] = t + 1;
            }
        }
    } else {
        // ================= Q: L2 pipeline, self-paced =================
#pragma unroll 4
        for (int u = 0; u < Tt; ++u) {
            poll_flags(flg, u + 1, u, lane);   // h1(u) ready + own group done u-1
            // ---- finalize out(u-2) -> LDS outbuf (lag 2, off-chain) ----
            if (u > 1 && w == 4 && lane < NBat) {
                f32x4 v = *(const f32x4*)&headp[(u - 2) & 3][lane][0];
                outbuf[lane * Tt + (u - 2)] = blin + (v[0] + v[1]) + (v[2] + v[3]);
            }
            // ---- a2(u) = W2.h1(u) + W3.h2(u-1) + b2 (pre-scaled) ----
            const _Float16* h1p = h1ring[u & (RING - 1)] + bsel * HSTR;
            const _Float16* h2p = h2buf[(u + 1) & 1] + bsel * HSTR;  // (u-1) parity
            const f16x8 pa0 = *(const f16x8*)(h1p + quad * 8);
            const f16x8 pa1 = *(const f16x8*)(h1p + 32 + quad * 8);
            const f16x8 pb0 = *(const f16x8*)(h2p + quad * 8);
            const f16x8 pb1 = *(const f16x8*)(h2p + 32 + quad * 8);
            f32x4 acc[4];
            __builtin_amdgcn_s_setprio(1);
#pragma unroll
            for (int q = 0; q < 4; ++q) {   // two independent 2-deep chains
                f32x4 p2 = __builtin_amdgcn_mfma_f32_16x16x32_f16(wfA[q][0], pa0, bv[q], 0, 0, 0);
                p2 = __builtin_amdgcn_mfma_f32_16x16x32_f16(wfA[q][1], pa1, p2, 0, 0, 0);
                f32x4 p3 = __builtin_amdgcn_mfma_f32_16x16x32_f16(wfB[q][0], pb0, f32x4{0,0,0,0}, 0, 0, 0);
                p3 = __builtin_amdgcn_mfma_f32_16x16x32_f16(wfB[q][1], pb1, p3, 0, 0, 0);
                acc[q] = p2 + p3;
            }
            __builtin_amdgcn_s_setprio(0);
            // ---- register mux + cell ----
            f32x4 g;
#pragma unroll
            for (int r = 0; r < 4; ++r) {
                float lo = s1 ? acc[1][r] : acc[0][r];
                float hi = s1 ? acc[3][r] : acc[2][r];
                g[r] = s2 ? hi : lo;
            }
            float ig = sigm_pre(g[0]), fg = sigm_pre(g[1]);
            float gg = tanh_pre(g[2]), og = sigm_pre(g[3]);
            cst = fmaf(fg, cst, ig * gg);
            float h = og * tanh_f(cst);
            h2buf[u & 1][hidx] = (_Float16)h;
            if (lane == 0) {          // publish right after h2 write
                asm volatile("" ::: "memory");
                *(volatile int*)&flg[4 + gw] = u + 1;
            }
            // ---- head partial AFTER publish (off-chain; w4 reads lag-2) ----
            float p = h * wl_u;                // sum over own wave's 16 units
            p += __shfl_xor(p, 4);
            p += __shfl_xor(p, 8);
            p += __shfl_xor(p, 16);
            p += __shfl_xor(p, 32);
            if (lane < NBat)                   // lane==bsel, full slice sum
                headp[u & 3][lane][gw] = p;
        }
        // ---- tail-done: order the FINAL headp write (race fixed in R27) ----
        if (lane == 0) {
            asm volatile("" ::: "memory");
            *(volatile int*)&flg2[gw] = 1;
        }
        // ---- tail: out(Tt-2), out(Tt-1) after ALL headp(Tt-1) visible ----
        if (w == 4) {
            for (;;) {
                int a = ((const volatile int*)flg2)[0];
                int b = ((const volatile int*)flg2)[1];
                int c = ((const volatile int*)flg2)[2];
                int d = ((const volatile int*)flg2)[3];
                if ((a & b & c & d) != 0) break;
            }
            __builtin_amdgcn_sched_barrier(0);
            asm volatile("" ::: "memory");
            if (lane < NBat) {
                f32x4 v2 = *(const f32x4*)&headp[(Tt - 2) & 3][lane][0];
                outbuf[lane * Tt + (Tt - 2)] = blin + (v2[0] + v2[1]) + (v2[2] + v2[3]);
                f32x4 v1 = *(const f32x4*)&headp[(Tt - 1) & 3][lane][0];
                outbuf[lane * Tt + (Tt - 1)] = blin + (v1[0] + v1[1]) + (v1[2] + v1[3]);
            }
        }
    }
    __syncthreads();
    // ---- cooperative coalesced flush: LDS outbuf -> global out ----
    for (int i = tid; i < NBat * Tt; i += 512)
        st(out, (bb + (i >> 10)) * Tt + (i & 1023), outbuf[i], f32);
}

extern "C" void kernel_launch(void* const* d_in, const int* in_sizes, int n_in,
                              void* d_out, int out_size, void* d_ws, size_t ws_size,
                              hipStream_t stream)
{
    (void)in_sizes; (void)n_in; (void)out_size; (void)d_ws; (void)ws_size;
    lstm2_kernel<<<dim3(Bb / NBat), dim3(512), 0, stream>>>(
        d_in[0], d_in[1], d_in[2], d_in[3], d_in[4], d_in[5],
        d_in[6], d_in[7], d_in[8], d_in[9], d_in[10], d_out);
}